// Round 17
// baseline (817.915 us; speedup 1.0000x reference)
//
#include <hip/hip_runtime.h>

#define NUM_NODES 100000
#define INPUT_DIM 256
#define NUM_BAGS  2048
#define BAG_SIZE  64
#define N_EDGES   3200000
#define NQUAD     (N_EDGES / 4)   // 800000
#define P_PART    8
#define NPP       12500           // 50 KB static LDS hist
#define NSLICE    32              // rep rows (chunks in main path)
#define QPS       (NQUAD / NSLICE)
#define HEAP_CAP  ((size_t)N_EDGES)   // per-partition heap capacity (safe bound)
#define QPB       3125            // 800000 quads / 256 scatter blocks

typedef unsigned int u32;
typedef unsigned long long u64;
typedef float f4 __attribute__((ext_vector_type(4)));

// ---------------------------------------------------------------------------
// A (main): fused pack + partition scatter, single read of the edge list.
// Each wave stages (src<<15 | bf15(w)) words in per-wave per-partition 128-deep
// LDS rings; full 64-chunks flush with ONE wave atomicAdd + a coalesced 256 B
// store. Every edge is read once and written once (vs 8x rescan).
__global__ void __launch_bounds__(1024)
part_scatter(const int* __restrict__ edge_src, const int* __restrict__ edge_nbr,
             const float* __restrict__ nw,
             u32* __restrict__ heap,      // [8][HEAP_CAP]
             u32* __restrict__ gcur) {    // [8], pre-zeroed
    __shared__ u32 buf[16][8][128];       // 64 KB: [wave][partition][ring]
    const int wv   = threadIdx.x >> 6;
    const int lane = threadIdx.x & 63;
    const u64 lt   = (1ull << lane) - 1ull;

    u32 cnt[8]     = {0, 0, 0, 0, 0, 0, 0, 0};
    u32 flushed[8] = {0, 0, 0, 0, 0, 0, 0, 0};

    const int base_q = blockIdx.x * QPB;
    #pragma unroll 1
    for (int s = 0; s < 4; ++s) {
        const int off   = s * 1024 + (int)threadIdx.x;
        const bool valid = off < QPB;
        uint4 s4 = make_uint4(0, 0, 0, 0), n4 = make_uint4(0, 0, 0, 0);
        if (valid) {
            s4 = ((const uint4*)edge_src)[base_q + off];
            n4 = ((const uint4*)edge_nbr)[base_q + off];
        }
        u32 words[4], ps[4];
#define PREP(SL, S, N)                                                        \
        {                                                                     \
            const u32 wb = valid ?                                            \
                ((__float_as_uint(nw[(N)]) + 0x8000u) >> 16) & 0x7FFFu : 0u;  \
            words[SL] = ((S) << 15) | wb;                                     \
            ps[SL]    = valid ? (S) / (u32)NPP : 8u;   /* 8 = no partition */ \
        }
        PREP(0, s4.x, n4.x)
        PREP(1, s4.y, n4.y)
        PREP(2, s4.z, n4.z)
        PREP(3, s4.w, n4.w)
#undef PREP
        #pragma unroll
        for (int sl = 0; sl < 4; ++sl) {
            const u32 p    = ps[sl];
            const u32 word = words[sl];
            #pragma unroll
            for (u32 pp = 0; pp < 8; ++pp) {
                const u64 m = __ballot(p == pp);
                if (m == 0ull) continue;                   // wave-uniform skip
                if (p == pp) {
                    const u32 rank = (u32)__popcll(m & lt);
                    buf[wv][pp][(cnt[pp] + rank) & 127u] = word;
                }
                cnt[pp] += (u32)__popcll(m);
                if (cnt[pp] - flushed[pp] >= 64u) {        // wave-uniform
                    u32 gbase = 0;
                    if (lane == 0) gbase = atomicAdd(&gcur[pp], 64u);
                    gbase = (u32)__shfl((int)gbase, 0);
                    heap[(size_t)pp * HEAP_CAP + gbase + lane] =
                        buf[wv][pp][(flushed[pp] + (u32)lane) & 127u];
                    flushed[pp] += 64u;
                }
            }
        }
    }
    // drain partial rings (rem <= 63 by the flush invariant)
    #pragma unroll
    for (u32 pp = 0; pp < 8; ++pp) {
        const u32 rem = cnt[pp] - flushed[pp];
        if (rem) {
            u32 gbase = 0;
            if (lane == 0) gbase = atomicAdd(&gcur[pp], rem);
            gbase = (u32)__shfl((int)gbase, 0);
            if ((u32)lane < rem)
                heap[(size_t)pp * HEAP_CAP + gbase + lane] =
                    buf[wv][pp][(flushed[pp] + (u32)lane) & 127u];
        }
    }
}

// B (main): hist over partitioned heap — each edge read ONCE, no predicate.
// Block (p, c): chunk c of partition p's heap; 50 KB LDS hist; f4 NT flush
// to rep[c][p*NPP ..]. All 32 rows x 8 segments covered exactly once.
__global__ void __launch_bounds__(1024)
heap_hist(const u32* __restrict__ heap, const u32* __restrict__ gcur,
          float* __restrict__ rep) {
    __shared__ float hist[NPP];
    const int p    = blockIdx.x >> 5;      // 0..7
    const int c    = blockIdx.x & 31;      // 0..31
    const int base = p * NPP;

    for (int j = threadIdx.x; j < NPP / 4; j += 1024)
        ((f4*)hist)[j] = (f4){0.f, 0.f, 0.f, 0.f};
    __syncthreads();

    const u32 tot = gcur[p];
    const u32 cs  = (tot + 31u) >> 5;
    const u32 lo  = (u32)c * cs;
    const u32 hi  = (lo + cs < tot) ? lo + cs : tot;
    for (u32 i = lo + threadIdx.x; i < hi; i += 1024) {
        const u32 w = heap[(size_t)p * HEAP_CAP + i];
        atomicAdd(&hist[(w >> 15) - (u32)base],
                  __uint_as_float((w & 0x7FFFu) << 16));
    }
    __syncthreads();

    float* dst = rep + (size_t)c * NUM_NODES + base;
    for (int j = threadIdx.x; j < NPP / 4; j += 1024) {
        const f4 v = ((const f4*)hist)[j];
        __builtin_nontemporal_store(v, &((f4*)dst)[j]);
    }
}

// ---------------------------------------------------------------------------
// Fallback A (R13): pack only.
__global__ void __launch_bounds__(256)
pack_edges(const int* __restrict__ edge_src, const int* __restrict__ edge_nbr,
           const float* __restrict__ nw, u32* __restrict__ packed) {
    const int q = blockIdx.x * 256 + threadIdx.x;
    const int4 s4 = ((const int4*)edge_src)[q];
    const int4 n4 = ((const int4*)edge_nbr)[q];
#define PACK(S, N)  (((u32)(S) << 15) |                                     \
                     (((__float_as_uint(nw[(N)]) + 0x8000u) >> 16) & 0x7FFFu))
    uint4 o;
    o.x = PACK(s4.x, n4.x);
    o.y = PACK(s4.y, n4.y);
    o.z = PACK(s4.z, n4.z);
    o.w = PACK(s4.w, n4.w);
#undef PACK
    ((uint4*)packed)[q] = o;
}

// Fallback B (R13): P=8 rescan hist.
__global__ void __launch_bounds__(1024)
hist_p(const u32* __restrict__ packed, float* __restrict__ rep) {
    __shared__ float hist[NPP];
    const int i    = blockIdx.x;
    const int r    = i & 7;
    const int p    = (i >> 3) & 7;
    const int b    = r | ((i >> 6) << 3);
    const int base = p * NPP;

    for (int j = threadIdx.x; j < NPP / 4; j += 1024)
        ((f4*)hist)[j] = (f4){0.f, 0.f, 0.f, 0.f};
    __syncthreads();

    const int lo = b * QPS;
#define EDGE(W)                                                          \
        {                                                                \
            const u32 rel = ((W) >> 15) - (u32)base;                     \
            if (rel < (u32)NPP)                                          \
                atomicAdd(&hist[rel],                                    \
                          __uint_as_float(((W) & 0x7FFFu) << 16));       \
        }
    for (int q = lo + (int)threadIdx.x; q < lo + QPS; q += 1024) {
        const uint4 a = ((const uint4*)packed)[q];
        EDGE(a.x) EDGE(a.y) EDGE(a.z) EDGE(a.w)
    }
#undef EDGE
    __syncthreads();

    float* dst = rep + (size_t)b * NUM_NODES + base;
    for (int j = threadIdx.x; j < NPP / 4; j += 1024) {
        const f4 v = ((const f4*)hist)[j];
        __builtin_nontemporal_store(v, &((f4*)dst)[j]);
    }
}

// Fused: blocks [0,RED_BLK) reduce rep -> nbr_sum; rest dense GEMV.
#define RED_BLK 98
__global__ void __launch_bounds__(256)
gemv_reduce(const float* __restrict__ rep, float* __restrict__ nbr_sum,
            const float* __restrict__ x, const float* __restrict__ theta,
            float* __restrict__ h) {
    if (blockIdx.x < RED_BLK) {
        const int i = blockIdx.x * 256 + threadIdx.x;
        if (i >= NUM_NODES / 4) return;
        float4 a = make_float4(0.f, 0.f, 0.f, 0.f);
        #pragma unroll 8
        for (int r = 0; r < NSLICE; ++r) {
            const float4 v = ((const float4*)(rep + (size_t)r * NUM_NODES))[i];
            a.x += v.x; a.y += v.y; a.z += v.z; a.w += v.w;
        }
        float4 o;
        o.x = a.x > 0.f ? a.x : 1.0f;
        o.y = a.y > 0.f ? a.y : 1.0f;
        o.z = a.z > 0.f ? a.z : 1.0f;
        o.w = a.w > 0.f ? a.w : 1.0f;
        ((float4*)nbr_sum)[i] = o;
    } else {
        const int gb   = blockIdx.x - RED_BLK;
        const int lane = threadIdx.x & 63;
        const int wave = threadIdx.x >> 6;
        const float4 tw = *reinterpret_cast<const float4*>(&theta[lane * 4]);
        for (int row = gb * 4 + wave; row < NUM_NODES; row += 2048 * 4) {
            const float4 xv =
                *reinterpret_cast<const float4*>(&x[(size_t)row * INPUT_DIM + lane * 4]);
            float d = xv.x * tw.x + xv.y * tw.y + xv.z * tw.z + xv.w * tw.w;
            #pragma unroll
            for (int off = 32; off >= 1; off >>= 1)
                d += __shfl_xor(d, off);
            if (lane == 0) h[row] = d;
        }
    }
}

// Final: out[bag] = sum_item h[idx] * nbr_sum[idx] * alpha
__global__ void __launch_bounds__(256)
bag_final(const int* __restrict__ bags, const float* __restrict__ alpha,
          const float* __restrict__ h, const float* __restrict__ ns,
          float* __restrict__ out) {
    const int bag  = blockIdx.x * 4 + (threadIdx.x >> 6);
    const int lane = threadIdx.x & 63;
    const int idx  = bags[bag * BAG_SIZE + lane];
    float v = h[idx] * ns[idx] * alpha[bag * BAG_SIZE + lane];
    #pragma unroll
    for (int off = 32; off >= 1; off >>= 1)
        v += __shfl_xor(v, off);
    if (lane == 0) out[bag] = v;
}

// Tiny-ws fallback.
__global__ void __launch_bounds__(256)
edge_atomic(const int* __restrict__ edge_src, const int* __restrict__ edge_nbr,
            const float* __restrict__ nw, float* __restrict__ nbr_sum) {
    const int t = blockIdx.x * blockDim.x + threadIdx.x;
    const int4 s4 = ((const int4*)edge_src)[t];
    const int4 n4 = ((const int4*)edge_nbr)[t];
    atomicAdd(&nbr_sum[s4.x], nw[n4.x]);
    atomicAdd(&nbr_sum[s4.y], nw[n4.y]);
    atomicAdd(&nbr_sum[s4.z], nw[n4.z]);
    atomicAdd(&nbr_sum[s4.w], nw[n4.w]);
}

__global__ void __launch_bounds__(256)
fixup_nosum(float* __restrict__ nbr_sum) {
    const int i = blockIdx.x * 256 + threadIdx.x;
    if (i < NUM_NODES && nbr_sum[i] == 0.f) nbr_sum[i] = 1.0f;
}

__global__ void __launch_bounds__(256)
gemv_h(const float* __restrict__ x, const float* __restrict__ theta,
       float* __restrict__ h) {
    const int lane = threadIdx.x & 63;
    const int wave = threadIdx.x >> 6;
    const float4 tw = *reinterpret_cast<const float4*>(&theta[lane * 4]);
    const int stride = gridDim.x * 4;
    for (int row = blockIdx.x * 4 + wave; row < NUM_NODES; row += stride) {
        const float4 xv =
            *reinterpret_cast<const float4*>(&x[(size_t)row * INPUT_DIM + lane * 4]);
        float d = xv.x * tw.x + xv.y * tw.y + xv.z * tw.z + xv.w * tw.w;
        #pragma unroll
        for (int off = 32; off >= 1; off >>= 1)
            d += __shfl_xor(d, off);
        if (lane == 0) h[row] = d;
    }
}

extern "C" void kernel_launch(void* const* d_in, const int* in_sizes, int n_in,
                              void* d_out, int out_size, void* d_ws, size_t ws_size,
                              hipStream_t stream) {
    const float* x            = (const float*)d_in[0];
    const int*   bags         = (const int*)d_in[1];
    const float* alpha        = (const float*)d_in[2];
    const int*   edge_src     = (const int*)d_in[3];
    const int*   edge_nbr     = (const int*)d_in[4];
    const float* node_weights = (const float*)d_in[5];
    const float* theta        = (const float*)d_in[6];
    float*       out          = (float*)d_out;

    // main ws: heap[8][N_EDGES] u32 | gcur[8] | rep[32][100000] f32 | ns | h
    const size_t need_main =
        (HEAP_CAP * P_PART + 8 + (size_t)NSLICE * NUM_NODES
         + 2 * (size_t)NUM_NODES) * 4;
    const size_t need_r13 =
        ((size_t)N_EDGES + (size_t)NSLICE * NUM_NODES + 2 * (size_t)NUM_NODES) * 4;

    if (ws_size >= need_main) {
        u32*   heap    = (u32*)d_ws;
        u32*   gcur    = heap + HEAP_CAP * P_PART;
        float* rep     = (float*)(gcur + 8);
        float* nbr_sum = rep + (size_t)NSLICE * NUM_NODES;
        float* h       = nbr_sum + NUM_NODES;

        hipMemsetAsync(gcur, 0, 8 * sizeof(u32), stream);
        part_scatter<<<256, 1024, 0, stream>>>(edge_src, edge_nbr,
                                               node_weights, heap, gcur);
        heap_hist<<<P_PART * NSLICE, 1024, 0, stream>>>(heap, gcur, rep);
        gemv_reduce<<<RED_BLK + 2048, 256, 0, stream>>>(rep, nbr_sum, x, theta, h);
        bag_final<<<NUM_BAGS / 4, 256, 0, stream>>>(bags, alpha, h, nbr_sum, out);
    } else if (ws_size >= need_r13) {
        u32*   packed  = (u32*)d_ws;
        float* rep     = (float*)d_ws + N_EDGES;
        float* nbr_sum = rep + (size_t)NSLICE * NUM_NODES;
        float* h       = nbr_sum + NUM_NODES;

        pack_edges<<<NQUAD / 256, 256, 0, stream>>>(edge_src, edge_nbr,
                                                    node_weights, packed);
        hist_p<<<P_PART * NSLICE, 1024, 0, stream>>>(packed, rep);
        gemv_reduce<<<RED_BLK + 2048, 256, 0, stream>>>(rep, nbr_sum, x, theta, h);
        bag_final<<<NUM_BAGS / 4, 256, 0, stream>>>(bags, alpha, h, nbr_sum, out);
    } else {
        float* nbr_sum = (float*)d_ws;
        float* h       = nbr_sum + NUM_NODES;
        hipMemsetAsync(nbr_sum, 0, (size_t)NUM_NODES * 4, stream);
        edge_atomic<<<(N_EDGES / 4) / 256, 256, 0, stream>>>(
            edge_src, edge_nbr, node_weights, nbr_sum);
        fixup_nosum<<<(NUM_NODES + 255) / 256, 256, 0, stream>>>(nbr_sum);
        gemv_h<<<2048, 256, 0, stream>>>(x, theta, h);
        bag_final<<<NUM_BAGS / 4, 256, 0, stream>>>(bags, alpha, h, nbr_sum, out);
    }
}

// Round 18
// 75.539 us; speedup vs baseline: 10.8278x; 10.8278x over previous
//
#include <hip/hip_runtime.h>

#define NUM_NODES 100000
#define INPUT_DIM 256
#define NUM_BAGS  2048
#define BAG_SIZE  64
#define N_EDGES   3200000
#define NQUAD     (N_EDGES / 4)   // 800000

// Main path: P=4 partitions x 25000 nodes (100 KB dynamic LDS), 64 slices.
#define NPP4      25000
#define NSL4      64
#define QPS4      (NQUAD / NSL4)  // 12500 exact
// Fallback path (R13): P=8 x 12500 (50 KB static), 32 slices.
#define NPP8      12500
#define NSL8      32
#define QPS8      (NQUAD / NSL8)  // 25000

typedef unsigned int u32;
typedef unsigned short u16;
typedef float f4 __attribute__((ext_vector_type(4)));
typedef u32   u4 __attribute__((ext_vector_type(4)));

// ---------------------------------------------------------------------------
// Pass A: pack (src, w) into one u32 per edge.
//   word = (src << 15) | bf15(nw[nbr])   (weights in [0,1) -> sign bit 0)
__global__ void __launch_bounds__(256)
pack_edges(const int* __restrict__ edge_src, const int* __restrict__ edge_nbr,
           const float* __restrict__ nw, u32* __restrict__ packed) {
    const int q = blockIdx.x * 256 + threadIdx.x;
    const int4 s4 = ((const int4*)edge_src)[q];
    const int4 n4 = ((const int4*)edge_nbr)[q];
#define PACK(S, N)  (((u32)(S) << 15) |                                     \
                     (((__float_as_uint(nw[(N)]) + 0x8000u) >> 16) & 0x7FFFu))
    uint4 o;
    o.x = PACK(s4.x, n4.x);
    o.y = PACK(s4.y, n4.y);
    o.z = PACK(s4.z, n4.z);
    o.w = PACK(s4.w, n4.w);
#undef PACK
    ((uint4*)packed)[q] = o;
}

// Pass B (main): P=4 hist, 100 KB dynamic LDS, bf16 flush.
// Rescan = 4 x 12.8 = 51.2 MB (half of R13); flush = 12.8 MB bf16.
__global__ void __launch_bounds__(1024)
hist4(const u32* __restrict__ packed, u16* __restrict__ rep16) {
    extern __shared__ float hist[];            // NPP4 floats = 100 KB
    const int p    = blockIdx.x & 3;
    const int b    = blockIdx.x >> 2;          // 0..63
    const int base = p * NPP4;

    for (int j = threadIdx.x; j < NPP4 / 4; j += 1024)
        ((f4*)hist)[j] = (f4){0.f, 0.f, 0.f, 0.f};
    __syncthreads();

    const int lo = b * QPS4;
#define EDGE(W)                                                          \
        {                                                                \
            const u32 rel = ((W) >> 15) - (u32)base;                     \
            if (rel < (u32)NPP4)                                         \
                atomicAdd(&hist[rel],                                    \
                          __uint_as_float(((W) & 0x7FFFu) << 16));       \
        }
    for (int q = lo + (int)threadIdx.x; q < lo + QPS4; q += 1024) {
        const uint4 a = ((const uint4*)packed)[q];
        EDGE(a.x) EDGE(a.y) EDGE(a.z) EDGE(a.w)
    }
#undef EDGE
    __syncthreads();

    // bf16 flush: 8 nodes / thread-store (uint4 of 8 bf16), NT.
    u16* dst = rep16 + (size_t)b * NUM_NODES + base;   // 16B-aligned
    for (int j = threadIdx.x; j < NPP4 / 8; j += 1024) {
        u4 v;
        #pragma unroll
        for (int k = 0; k < 4; ++k) {
            const u32 lo_b = (__float_as_uint(hist[j * 8 + 2 * k])     + 0x8000u) >> 16;
            const u32 hi_b = (__float_as_uint(hist[j * 8 + 2 * k + 1]) + 0x8000u) >> 16;
            v[k] = lo_b | (hi_b << 16);
        }
        __builtin_nontemporal_store(v, &((u4*)dst)[j]);
    }
}

// Pass B (fallback, R13): P=8 static-LDS hist, f32 rep.
__global__ void __launch_bounds__(1024)
hist_p(const u32* __restrict__ packed, float* __restrict__ rep) {
    __shared__ float hist[NPP8];
    const int i    = blockIdx.x;
    const int r    = i & 7;
    const int p    = (i >> 3) & 7;
    const int b    = r | ((i >> 6) << 3);
    const int base = p * NPP8;

    for (int j = threadIdx.x; j < NPP8 / 4; j += 1024)
        ((f4*)hist)[j] = (f4){0.f, 0.f, 0.f, 0.f};
    __syncthreads();

    const int lo = b * QPS8;
#define EDGE(W)                                                          \
        {                                                                \
            const u32 rel = ((W) >> 15) - (u32)base;                     \
            if (rel < (u32)NPP8)                                         \
                atomicAdd(&hist[rel],                                    \
                          __uint_as_float(((W) & 0x7FFFu) << 16));       \
        }
    for (int q = lo + (int)threadIdx.x; q < lo + QPS8; q += 1024) {
        const uint4 a = ((const uint4*)packed)[q];
        EDGE(a.x) EDGE(a.y) EDGE(a.z) EDGE(a.w)
    }
#undef EDGE
    __syncthreads();

    float* dst = rep + (size_t)b * NUM_NODES + base;
    for (int j = threadIdx.x; j < NPP8 / 4; j += 1024) {
        const f4 v = ((const f4*)hist)[j];
        __builtin_nontemporal_store(v, &((f4*)dst)[j]);
    }
}

// mark used rows (bag members) so gemv can skip unreferenced rows (~27%).
__global__ void __launch_bounds__(256)
mark_used(const int* __restrict__ bags, unsigned char* __restrict__ used) {
    const int i = blockIdx.x * 256 + threadIdx.x;   // 131072 total
    used[bags[i]] = 1;
}

// Fused (main): blocks [0,RED4) reduce bf16 rep -> nbr_sum; rest: used-masked
// dense GEMV.
#define RED4 49   // ceil(12500 uint4-groups / 256)
__global__ void __launch_bounds__(256)
gemv_reduce4(const u16* __restrict__ rep16, float* __restrict__ nbr_sum,
             const float* __restrict__ x, const float* __restrict__ theta,
             float* __restrict__ h, const unsigned char* __restrict__ used) {
    if (blockIdx.x < RED4) {
        const int g = blockIdx.x * 256 + threadIdx.x;   // 8-node group
        if (g >= NUM_NODES / 8) return;
        float acc[8] = {0.f, 0.f, 0.f, 0.f, 0.f, 0.f, 0.f, 0.f};
        #pragma unroll 4
        for (int r = 0; r < NSL4; ++r) {
            const u4 v = ((const u4*)(rep16 + (size_t)r * NUM_NODES))[g];
            #pragma unroll
            for (int k = 0; k < 4; ++k) {
                acc[2 * k]     += __uint_as_float(v[k] << 16);
                acc[2 * k + 1] += __uint_as_float(v[k] & 0xFFFF0000u);
            }
        }
        float4 o0, o1;
        o0.x = acc[0] > 0.f ? acc[0] : 1.0f;
        o0.y = acc[1] > 0.f ? acc[1] : 1.0f;
        o0.z = acc[2] > 0.f ? acc[2] : 1.0f;
        o0.w = acc[3] > 0.f ? acc[3] : 1.0f;
        o1.x = acc[4] > 0.f ? acc[4] : 1.0f;
        o1.y = acc[5] > 0.f ? acc[5] : 1.0f;
        o1.z = acc[6] > 0.f ? acc[6] : 1.0f;
        o1.w = acc[7] > 0.f ? acc[7] : 1.0f;
        ((float4*)nbr_sum)[2 * g]     = o0;
        ((float4*)nbr_sum)[2 * g + 1] = o1;
    } else {
        const int gb   = blockIdx.x - RED4;
        const int lane = threadIdx.x & 63;
        const int wave = threadIdx.x >> 6;
        const float4 tw = *reinterpret_cast<const float4*>(&theta[lane * 4]);
        for (int row = gb * 4 + wave; row < NUM_NODES; row += 2048 * 4) {
            if (!used[row]) continue;                 // wave-uniform skip
            const float4 xv =
                *reinterpret_cast<const float4*>(&x[(size_t)row * INPUT_DIM + lane * 4]);
            float d = xv.x * tw.x + xv.y * tw.y + xv.z * tw.z + xv.w * tw.w;
            #pragma unroll
            for (int off = 32; off >= 1; off >>= 1)
                d += __shfl_xor(d, off);
            if (lane == 0) h[row] = d;
        }
    }
}

// Fused (fallback, R13): f32 rep reduce + unmasked GEMV.
#define RED_BLK 98
__global__ void __launch_bounds__(256)
gemv_reduce(const float* __restrict__ rep, float* __restrict__ nbr_sum,
            const float* __restrict__ x, const float* __restrict__ theta,
            float* __restrict__ h) {
    if (blockIdx.x < RED_BLK) {
        const int i = blockIdx.x * 256 + threadIdx.x;
        if (i >= NUM_NODES / 4) return;
        float4 a = make_float4(0.f, 0.f, 0.f, 0.f);
        #pragma unroll 8
        for (int r = 0; r < NSL8; ++r) {
            const float4 v = ((const float4*)(rep + (size_t)r * NUM_NODES))[i];
            a.x += v.x; a.y += v.y; a.z += v.z; a.w += v.w;
        }
        float4 o;
        o.x = a.x > 0.f ? a.x : 1.0f;
        o.y = a.y > 0.f ? a.y : 1.0f;
        o.z = a.z > 0.f ? a.z : 1.0f;
        o.w = a.w > 0.f ? a.w : 1.0f;
        ((float4*)nbr_sum)[i] = o;
    } else {
        const int gb   = blockIdx.x - RED_BLK;
        const int lane = threadIdx.x & 63;
        const int wave = threadIdx.x >> 6;
        const float4 tw = *reinterpret_cast<const float4*>(&theta[lane * 4]);
        for (int row = gb * 4 + wave; row < NUM_NODES; row += 2048 * 4) {
            const float4 xv =
                *reinterpret_cast<const float4*>(&x[(size_t)row * INPUT_DIM + lane * 4]);
            float d = xv.x * tw.x + xv.y * tw.y + xv.z * tw.z + xv.w * tw.w;
            #pragma unroll
            for (int off = 32; off >= 1; off >>= 1)
                d += __shfl_xor(d, off);
            if (lane == 0) h[row] = d;
        }
    }
}

// Final: out[bag] = sum_item h[idx] * nbr_sum[idx] * alpha
__global__ void __launch_bounds__(256)
bag_final(const int* __restrict__ bags, const float* __restrict__ alpha,
          const float* __restrict__ h, const float* __restrict__ ns,
          float* __restrict__ out) {
    const int bag  = blockIdx.x * 4 + (threadIdx.x >> 6);
    const int lane = threadIdx.x & 63;
    const int idx  = bags[bag * BAG_SIZE + lane];
    float v = h[idx] * ns[idx] * alpha[bag * BAG_SIZE + lane];
    #pragma unroll
    for (int off = 32; off >= 1; off >>= 1)
        v += __shfl_xor(v, off);
    if (lane == 0) out[bag] = v;
}

// Tiny-ws fallback.
__global__ void __launch_bounds__(256)
edge_atomic(const int* __restrict__ edge_src, const int* __restrict__ edge_nbr,
            const float* __restrict__ nw, float* __restrict__ nbr_sum) {
    const int t = blockIdx.x * blockDim.x + threadIdx.x;
    const int4 s4 = ((const int4*)edge_src)[t];
    const int4 n4 = ((const int4*)edge_nbr)[t];
    atomicAdd(&nbr_sum[s4.x], nw[n4.x]);
    atomicAdd(&nbr_sum[s4.y], nw[n4.y]);
    atomicAdd(&nbr_sum[s4.z], nw[n4.z]);
    atomicAdd(&nbr_sum[s4.w], nw[n4.w]);
}

__global__ void __launch_bounds__(256)
fixup_nosum(float* __restrict__ nbr_sum) {
    const int i = blockIdx.x * 256 + threadIdx.x;
    if (i < NUM_NODES && nbr_sum[i] == 0.f) nbr_sum[i] = 1.0f;
}

__global__ void __launch_bounds__(256)
gemv_h(const float* __restrict__ x, const float* __restrict__ theta,
       float* __restrict__ h) {
    const int lane = threadIdx.x & 63;
    const int wave = threadIdx.x >> 6;
    const float4 tw = *reinterpret_cast<const float4*>(&theta[lane * 4]);
    const int stride = gridDim.x * 4;
    for (int row = blockIdx.x * 4 + wave; row < NUM_NODES; row += stride) {
        const float4 xv =
            *reinterpret_cast<const float4*>(&x[(size_t)row * INPUT_DIM + lane * 4]);
        float d = xv.x * tw.x + xv.y * tw.y + xv.z * tw.z + xv.w * tw.w;
        #pragma unroll
        for (int off = 32; off >= 1; off >>= 1)
            d += __shfl_xor(d, off);
        if (lane == 0) h[row] = d;
    }
}

extern "C" void kernel_launch(void* const* d_in, const int* in_sizes, int n_in,
                              void* d_out, int out_size, void* d_ws, size_t ws_size,
                              hipStream_t stream) {
    const float* x            = (const float*)d_in[0];
    const int*   bags         = (const int*)d_in[1];
    const float* alpha        = (const float*)d_in[2];
    const int*   edge_src     = (const int*)d_in[3];
    const int*   edge_nbr     = (const int*)d_in[4];
    const float* node_weights = (const float*)d_in[5];
    const float* theta        = (const float*)d_in[6];
    float*       out          = (float*)d_out;

    // main ws: packed[3.2M] u32 | rep16[64][100000] u16 | nbr_sum f32 |
    //          h f32 | used u8[100000]
    const size_t need4 = (size_t)N_EDGES * 4 + (size_t)NSL4 * NUM_NODES * 2
                       + 2 * (size_t)NUM_NODES * 4 + NUM_NODES;
    const size_t need8 =
        ((size_t)N_EDGES + (size_t)NSL8 * NUM_NODES + 2 * (size_t)NUM_NODES) * 4;

    const hipError_t attr_ok = hipFuncSetAttribute(
        (const void*)hist4, hipFuncAttributeMaxDynamicSharedMemorySize,
        NPP4 * (int)sizeof(float));

    if (attr_ok == hipSuccess && ws_size >= need4) {
        u32*   packed  = (u32*)d_ws;
        u16*   rep16   = (u16*)(packed + N_EDGES);
        float* nbr_sum = (float*)(rep16 + (size_t)NSL4 * NUM_NODES);
        float* h       = nbr_sum + NUM_NODES;
        unsigned char* used = (unsigned char*)(h + NUM_NODES);

        hipMemsetAsync(used, 0, NUM_NODES, stream);
        mark_used<<<(NUM_BAGS * BAG_SIZE) / 256, 256, 0, stream>>>(bags, used);
        pack_edges<<<NQUAD / 256, 256, 0, stream>>>(edge_src, edge_nbr,
                                                    node_weights, packed);
        hist4<<<4 * NSL4, 1024, NPP4 * sizeof(float), stream>>>(packed, rep16);
        gemv_reduce4<<<RED4 + 2048, 256, 0, stream>>>(rep16, nbr_sum, x, theta,
                                                      h, used);
        bag_final<<<NUM_BAGS / 4, 256, 0, stream>>>(bags, alpha, h, nbr_sum, out);
    } else if (ws_size >= need8) {
        u32*   packed  = (u32*)d_ws;
        float* rep     = (float*)d_ws + N_EDGES;
        float* nbr_sum = rep + (size_t)NSL8 * NUM_NODES;
        float* h       = nbr_sum + NUM_NODES;

        pack_edges<<<NQUAD / 256, 256, 0, stream>>>(edge_src, edge_nbr,
                                                    node_weights, packed);
        hist_p<<<8 * NSL8, 1024, 0, stream>>>(packed, rep);
        gemv_reduce<<<RED_BLK + 2048, 256, 0, stream>>>(rep, nbr_sum, x, theta, h);
        bag_final<<<NUM_BAGS / 4, 256, 0, stream>>>(bags, alpha, h, nbr_sum, out);
    } else {
        float* nbr_sum = (float*)d_ws;
        float* h       = nbr_sum + NUM_NODES;
        hipMemsetAsync(nbr_sum, 0, (size_t)NUM_NODES * 4, stream);
        edge_atomic<<<(N_EDGES / 4) / 256, 256, 0, stream>>>(
            edge_src, edge_nbr, node_weights, nbr_sum);
        fixup_nosum<<<(NUM_NODES + 255) / 256, 256, 0, stream>>>(nbr_sum);
        gemv_h<<<2048, 256, 0, stream>>>(x, theta, h);
        bag_final<<<NUM_BAGS / 4, 256, 0, stream>>>(bags, alpha, h, nbr_sum, out);
    }
}

// Round 19
// 70.702 us; speedup vs baseline: 11.5685x; 1.0684x over previous
//
#include <hip/hip_runtime.h>

#define NUM_NODES 100000
#define INPUT_DIM 256
#define NUM_BAGS  2048
#define BAG_SIZE  64
#define N_EDGES   3200000
#define NQUAD     (N_EDGES / 4)   // 800000
#define P_PART    8
#define NPP       12500           // 50 KB static LDS
#define NSLICE    32
#define QPS       (NQUAD / NSLICE)   // 25000
#define PACK_BLK  (NQUAD / 256)      // 3125
#define MARK_BLK  ((NUM_BAGS * BAG_SIZE) / 256)   // 512

typedef unsigned int u32;
typedef float f4 __attribute__((ext_vector_type(4)));

// Pass A: pack (src, w) into one u32 per edge; extra blocks mark used rows.
//   word = (src << 15) | bf15(nw[nbr])   (weights in [0,1) -> sign bit 0)
__global__ void __launch_bounds__(256)
pack_mark(const int* __restrict__ edge_src, const int* __restrict__ edge_nbr,
          const float* __restrict__ nw, u32* __restrict__ packed,
          const int* __restrict__ bags, unsigned char* __restrict__ used) {
    if (blockIdx.x < PACK_BLK) {
        const int q = blockIdx.x * 256 + threadIdx.x;
        const int4 s4 = ((const int4*)edge_src)[q];
        const int4 n4 = ((const int4*)edge_nbr)[q];
#define PACK(S, N)  (((u32)(S) << 15) |                                     \
                     (((__float_as_uint(nw[(N)]) + 0x8000u) >> 16) & 0x7FFFu))
        uint4 o;
        o.x = PACK(s4.x, n4.x);
        o.y = PACK(s4.y, n4.y);
        o.z = PACK(s4.z, n4.z);
        o.w = PACK(s4.w, n4.w);
#undef PACK
        ((uint4*)packed)[q] = o;
    } else {
        const int i = (blockIdx.x - PACK_BLK) * 256 + threadIdx.x;  // < 131072
        used[bags[i]] = 1;    // benign race
    }
}

// Pass B: P=8 partitioned LDS histogram (R13 exact; measured 20.7 us, R16).
__global__ void __launch_bounds__(1024)
hist_p(const u32* __restrict__ packed, float* __restrict__ rep) {
    __shared__ float hist[NPP];
    const int i    = blockIdx.x;
    const int r    = i & 7;
    const int p    = (i >> 3) & 7;
    const int b    = r | ((i >> 6) << 3);      // 0..31
    const int base = p * NPP;

    for (int j = threadIdx.x; j < NPP / 4; j += 1024)
        ((f4*)hist)[j] = (f4){0.f, 0.f, 0.f, 0.f};
    __syncthreads();

    const int lo = b * QPS;
#define EDGE(W)                                                          \
        {                                                                \
            const u32 rel = ((W) >> 15) - (u32)base;                     \
            if (rel < (u32)NPP)                                          \
                atomicAdd(&hist[rel],                                    \
                          __uint_as_float(((W) & 0x7FFFu) << 16));       \
        }
    for (int q = lo + (int)threadIdx.x; q < lo + QPS; q += 1024) {
        const uint4 a = ((const uint4*)packed)[q];
        EDGE(a.x) EDGE(a.y) EDGE(a.z) EDGE(a.w)
    }
#undef EDGE
    __syncthreads();

    float* dst = rep + (size_t)b * NUM_NODES + base;
    for (int j = threadIdx.x; j < NPP / 4; j += 1024) {
        const f4 v = ((const f4*)hist)[j];
        __builtin_nontemporal_store(v, &((f4*)dst)[j]);
    }
}

// Fused: blocks [0,RED_BLK) reduce rep -> nbr_sum; rest: used-masked GEMV.
#define RED_BLK 98
__global__ void __launch_bounds__(256)
gemv_reduce(const float* __restrict__ rep, float* __restrict__ nbr_sum,
            const float* __restrict__ x, const float* __restrict__ theta,
            float* __restrict__ h, const unsigned char* __restrict__ used) {
    if (blockIdx.x < RED_BLK) {
        const int i = blockIdx.x * 256 + threadIdx.x;
        if (i >= NUM_NODES / 4) return;
        float4 a = make_float4(0.f, 0.f, 0.f, 0.f);
        #pragma unroll 8
        for (int r = 0; r < NSLICE; ++r) {
            const float4 v = ((const float4*)(rep + (size_t)r * NUM_NODES))[i];
            a.x += v.x; a.y += v.y; a.z += v.z; a.w += v.w;
        }
        float4 o;
        o.x = a.x > 0.f ? a.x : 1.0f;
        o.y = a.y > 0.f ? a.y : 1.0f;
        o.z = a.z > 0.f ? a.z : 1.0f;
        o.w = a.w > 0.f ? a.w : 1.0f;
        ((float4*)nbr_sum)[i] = o;
    } else {
        const int gb   = blockIdx.x - RED_BLK;
        const int lane = threadIdx.x & 63;
        const int wave = threadIdx.x >> 6;
        const float4 tw = *reinterpret_cast<const float4*>(&theta[lane * 4]);
        for (int row = gb * 4 + wave; row < NUM_NODES; row += 2048 * 4) {
            if (!used[row]) continue;             // ~27% skipped, wave-uniform
            const float4 xv =
                *reinterpret_cast<const float4*>(&x[(size_t)row * INPUT_DIM + lane * 4]);
            float d = xv.x * tw.x + xv.y * tw.y + xv.z * tw.z + xv.w * tw.w;
            #pragma unroll
            for (int off = 32; off >= 1; off >>= 1)
                d += __shfl_xor(d, off);
            if (lane == 0) h[row] = d;
        }
    }
}

// Final: out[bag] = sum_item h[idx] * nbr_sum[idx] * alpha
__global__ void __launch_bounds__(256)
bag_final(const int* __restrict__ bags, const float* __restrict__ alpha,
          const float* __restrict__ h, const float* __restrict__ ns,
          float* __restrict__ out) {
    const int bag  = blockIdx.x * 4 + (threadIdx.x >> 6);
    const int lane = threadIdx.x & 63;
    const int idx  = bags[bag * BAG_SIZE + lane];
    float v = h[idx] * ns[idx] * alpha[bag * BAG_SIZE + lane];
    #pragma unroll
    for (int off = 32; off >= 1; off >>= 1)
        v += __shfl_xor(v, off);
    if (lane == 0) out[bag] = v;
}

// Tiny-ws fallback.
__global__ void __launch_bounds__(256)
edge_atomic(const int* __restrict__ edge_src, const int* __restrict__ edge_nbr,
            const float* __restrict__ nw, float* __restrict__ nbr_sum) {
    const int t = blockIdx.x * blockDim.x + threadIdx.x;
    const int4 s4 = ((const int4*)edge_src)[t];
    const int4 n4 = ((const int4*)edge_nbr)[t];
    atomicAdd(&nbr_sum[s4.x], nw[n4.x]);
    atomicAdd(&nbr_sum[s4.y], nw[n4.y]);
    atomicAdd(&nbr_sum[s4.z], nw[n4.z]);
    atomicAdd(&nbr_sum[s4.w], nw[n4.w]);
}

__global__ void __launch_bounds__(256)
fixup_nosum(float* __restrict__ nbr_sum) {
    const int i = blockIdx.x * 256 + threadIdx.x;
    if (i < NUM_NODES && nbr_sum[i] == 0.f) nbr_sum[i] = 1.0f;
}

__global__ void __launch_bounds__(256)
gemv_h(const float* __restrict__ x, const float* __restrict__ theta,
       float* __restrict__ h) {
    const int lane = threadIdx.x & 63;
    const int wave = threadIdx.x >> 6;
    const float4 tw = *reinterpret_cast<const float4*>(&theta[lane * 4]);
    const int stride = gridDim.x * 4;
    for (int row = blockIdx.x * 4 + wave; row < NUM_NODES; row += stride) {
        const float4 xv =
            *reinterpret_cast<const float4*>(&x[(size_t)row * INPUT_DIM + lane * 4]);
        float d = xv.x * tw.x + xv.y * tw.y + xv.z * tw.z + xv.w * tw.w;
        #pragma unroll
        for (int off = 32; off >= 1; off >>= 1)
            d += __shfl_xor(d, off);
        if (lane == 0) h[row] = d;
    }
}

extern "C" void kernel_launch(void* const* d_in, const int* in_sizes, int n_in,
                              void* d_out, int out_size, void* d_ws, size_t ws_size,
                              hipStream_t stream) {
    const float* x            = (const float*)d_in[0];
    const int*   bags         = (const int*)d_in[1];
    const float* alpha        = (const float*)d_in[2];
    const int*   edge_src     = (const int*)d_in[3];
    const int*   edge_nbr     = (const int*)d_in[4];
    const float* node_weights = (const float*)d_in[5];
    const float* theta        = (const float*)d_in[6];
    float*       out          = (float*)d_out;

    // ws: packed[3.2M] u32 | rep[32][100000] f32 | nbr_sum | h | used[100000] u8
    const size_t need_full =
        ((size_t)N_EDGES + (size_t)NSLICE * NUM_NODES + 2 * (size_t)NUM_NODES) * 4
        + NUM_NODES;

    if (ws_size >= need_full) {
        u32*   packed  = (u32*)d_ws;
        float* rep     = (float*)d_ws + N_EDGES;
        float* nbr_sum = rep + (size_t)NSLICE * NUM_NODES;
        float* h       = nbr_sum + NUM_NODES;
        unsigned char* used = (unsigned char*)(h + NUM_NODES);

        hipMemsetAsync(used, 0, NUM_NODES, stream);
        pack_mark<<<PACK_BLK + MARK_BLK, 256, 0, stream>>>(
            edge_src, edge_nbr, node_weights, packed, bags, used);
        hist_p<<<P_PART * NSLICE, 1024, 0, stream>>>(packed, rep);
        gemv_reduce<<<RED_BLK + 2048, 256, 0, stream>>>(rep, nbr_sum, x, theta,
                                                        h, used);
        bag_final<<<NUM_BAGS / 4, 256, 0, stream>>>(bags, alpha, h, nbr_sum, out);
    } else {
        float* nbr_sum = (float*)d_ws;
        float* h       = nbr_sum + NUM_NODES;
        hipMemsetAsync(nbr_sum, 0, (size_t)NUM_NODES * 4, stream);
        edge_atomic<<<(N_EDGES / 4) / 256, 256, 0, stream>>>(
            edge_src, edge_nbr, node_weights, nbr_sum);
        fixup_nosum<<<(NUM_NODES + 255) / 256, 256, 0, stream>>>(nbr_sum);
        gemv_h<<<2048, 256, 0, stream>>>(x, theta, h);
        bag_final<<<NUM_BAGS / 4, 256, 0, stream>>>(bags, alpha, h, nbr_sum, out);
    }
}